// Round 1
// baseline (1642.854 us; speedup 1.0000x reference)
//
#include <hip/hip_runtime.h>
#include <math.h>

#define B_ 8
#define S_ 2048
#define D_ 512

constexpr float INV_SCALE = 0.044194173824159216f; // 1/sqrt(512)

// ---------------- Kernel 1: xw = x @ W * inv_scale ----------------
// C[M,512] = A[M,512] @ W[512,512], M = B*S = 16384.
// 64x64 tile, K-step 16, 256 threads, 4x4 per thread.
__global__ __launch_bounds__(256) void xw_gemm(const float* __restrict__ A,
                                               const float* __restrict__ W,
                                               float* __restrict__ C) {
    __shared__ float As[16][65];   // [k][m], +1 pad
    __shared__ float Bs[16][64];   // [k][n]
    const int tid  = threadIdx.x;
    const int row0 = blockIdx.y * 64;
    const int col0 = blockIdx.x * 64;
    const int ty = tid / 16, tx = tid % 16;

    float acc[4][4] = {};

    const int ar = tid / 4;          // A row within tile (0..63)
    const int ak = (tid % 4) * 4;    // A k offset (float4)
    const int bk = tid / 16;         // B k row (0..15)
    const int bn = (tid % 16) * 4;   // B col offset (float4)

    for (int k0 = 0; k0 < 512; k0 += 16) {
        float4 a4 = *(const float4*)(A + (long)(row0 + ar) * 512 + k0 + ak);
        float4 b4 = *(const float4*)(W + (long)(k0 + bk) * 512 + col0 + bn);
        __syncthreads();
        As[ak + 0][ar] = a4.x; As[ak + 1][ar] = a4.y;
        As[ak + 2][ar] = a4.z; As[ak + 3][ar] = a4.w;
        *(float4*)&Bs[bk][bn] = b4;
        __syncthreads();
#pragma unroll
        for (int kk = 0; kk < 16; kk++) {
            float a[4], b[4];
#pragma unroll
            for (int i = 0; i < 4; i++) a[i] = As[kk][ty * 4 + i];
#pragma unroll
            for (int j = 0; j < 4; j++) b[j] = Bs[kk][tx * 4 + j];
#pragma unroll
            for (int i = 0; i < 4; i++)
#pragma unroll
                for (int j = 0; j < 4; j++)
                    acc[i][j] += a[i] * b[j];
        }
    }
#pragma unroll
    for (int i = 0; i < 4; i++) {
        float4 o = make_float4(acc[i][0] * INV_SCALE, acc[i][1] * INV_SCALE,
                               acc[i][2] * INV_SCALE, acc[i][3] * INV_SCALE);
        *(float4*)(C + (long)(row0 + ty * 4 + i) * 512 + col0 + tx * 4) = o;
    }
}

// ---------------- Kernel 2: flash attention (fp32) ----------------
// out[b,s,:] = softmax_t( xw[b,s,:] . x[b,t,:] ) @ x[b,:,:]
// 32 queries/block, 256 threads: thread (q,g) with q=tid>>3, g=tid&7 owns
// d-slice [g*64, g*64+64). Keys staged in LDS, TK=16 rows, slice stride 17
// float4 (skew) so the 8 g-groups hit disjoint bank quartets on b128 reads.
#define TQ 32
#define TK 16

__global__ __launch_bounds__(256) void flash_attn(const float* __restrict__ x,
                                                  const float* __restrict__ qw,
                                                  float* __restrict__ out) {
    __shared__ float4 kt[TK * 136];  // 16 rows * (8 slices * 17 f4) = 34816 B

    const int tid = threadIdx.x;
    const int q   = tid >> 3;
    const int g   = tid & 7;
    const int blk = blockIdx.x;
    const int b   = blk >> 6;            // 64 q-tiles per batch
    const int q0  = (blk & 63) * TQ;
    const int qrow = q0 + q;
    const long xbase = (long)b * S_ * D_;

    // Load this thread's qw slice into registers.
    float qwr[64];
    {
        const float4* p = (const float4*)(qw + xbase + (long)qrow * D_ + g * 64);
#pragma unroll
        for (int i4 = 0; i4 < 16; i4++) {
            float4 v = p[i4];
            qwr[4 * i4 + 0] = v.x; qwr[4 * i4 + 1] = v.y;
            qwr[4 * i4 + 2] = v.z; qwr[4 * i4 + 3] = v.w;
        }
    }
    float oa[64];
#pragma unroll
    for (int i = 0; i < 64; i++) oa[i] = 0.f;
    float m = -1e30f, l = 0.f;

    const float4* x4 = (const float4*)(x + xbase);

    for (int t0 = 0; t0 < S_; t0 += TK) {
        __syncthreads();
        // Stage TK key rows: 16*128 float4, 8 per thread, coalesced reads,
        // skewed LDS writes.
#pragma unroll
        for (int j = 0; j < 8; j++) {
            int f  = tid + j * 256;
            int tt = f >> 7;          // /128
            int c  = f & 127;         // float4 within row
            int gg = c >> 4, i4 = c & 15;
            kt[tt * 136 + gg * 17 + i4] = x4[(long)(t0 + tt) * 128 + c];
        }
        __syncthreads();
#pragma unroll 1
        for (int tt = 0; tt < TK; tt++) {
            float4 kv[16];
            const float4* kp = &kt[tt * 136 + g * 17];
#pragma unroll
            for (int i4 = 0; i4 < 16; i4++) kv[i4] = kp[i4];
            // partial dot over this thread's 64-wide d-slice
            float s = 0.f;
#pragma unroll
            for (int i4 = 0; i4 < 16; i4++) {
                s += qwr[4 * i4 + 0] * kv[i4].x + qwr[4 * i4 + 1] * kv[i4].y
                   + qwr[4 * i4 + 2] * kv[i4].z + qwr[4 * i4 + 3] * kv[i4].w;
            }
            // reduce across the 8 g-lanes (aligned 8-lane groups)
            s += __shfl_xor(s, 1, 64);
            s += __shfl_xor(s, 2, 64);
            s += __shfl_xor(s, 4, 64);
            // online softmax (rescale only when max moves — rare)
            if (s > m) {
                float alpha = __expf(m - s);
                l *= alpha;
#pragma unroll
                for (int i = 0; i < 64; i++) oa[i] *= alpha;
                m = s;
            }
            float p = __expf(s - m);
            l += p;
#pragma unroll
            for (int i4 = 0; i4 < 16; i4++) {
                oa[4 * i4 + 0] += p * kv[i4].x; oa[4 * i4 + 1] += p * kv[i4].y;
                oa[4 * i4 + 2] += p * kv[i4].z; oa[4 * i4 + 3] += p * kv[i4].w;
            }
        }
    }
    float inv_l = 1.0f / l;
    float4* op = (float4*)(out + xbase + (long)qrow * D_ + g * 64);
#pragma unroll
    for (int i4 = 0; i4 < 16; i4++) {
        op[i4] = make_float4(oa[4 * i4 + 0] * inv_l, oa[4 * i4 + 1] * inv_l,
                             oa[4 * i4 + 2] * inv_l, oa[4 * i4 + 3] * inv_l);
    }
}

extern "C" void kernel_launch(void* const* d_in, const int* in_sizes, int n_in,
                              void* d_out, int out_size, void* d_ws, size_t ws_size,
                              hipStream_t stream) {
    const float* x = (const float*)d_in[0];       // [B,S,D] fp32
    const float* W = (const float*)d_in[1];       // [D,D]   fp32
    float* out = (float*)d_out;                   // [B,S,D] fp32

    // xw buffer: prefer workspace; if ws too small, use d_out (safe: each
    // flash block reads only its own rows' qw before overwriting them).
    const size_t need = (size_t)B_ * S_ * D_ * sizeof(float); // 33.5 MB
    float* xw = (ws_size >= need) ? (float*)d_ws : out;

    dim3 g1(512 / 64, (B_ * S_) / 64);  // (8, 256)
    xw_gemm<<<g1, 256, 0, stream>>>(x, W, xw);
    flash_attn<<<B_ * (S_ / TQ), 256, 0, stream>>>(x, xw, out);
}

// Round 2
// 521.813 us; speedup vs baseline: 3.1484x; 3.1484x over previous
//
#include <hip/hip_runtime.h>
#include <math.h>

#define B_ 8
#define S_ 2048
#define D_ 512

typedef _Float16 half8 __attribute__((ext_vector_type(8)));
typedef _Float16 half4h __attribute__((ext_vector_type(4)));
typedef float f32x4 __attribute__((ext_vector_type(4)));

constexpr float INV_SCALE = 0.044194173824159216f; // 1/sqrt(512)

// ---------------- preprocess: x -> fp16 [t][d] and fp16 [d][t] ----------------
__global__ __launch_bounds__(256) void cvt_tr(const float* __restrict__ x,
                                              _Float16* __restrict__ xh,
                                              _Float16* __restrict__ xhT) {
    const int g = blockIdx.x * 256 + threadIdx.x;
    {   // job 1: linear convert, coalesced
        const size_t o = (size_t)g * 8;
        float4 f0 = *(const float4*)(x + o);
        float4 f1 = *(const float4*)(x + o + 4);
        half8 h = { (_Float16)f0.x, (_Float16)f0.y, (_Float16)f0.z, (_Float16)f0.w,
                    (_Float16)f1.x, (_Float16)f1.y, (_Float16)f1.z, (_Float16)f1.w };
        *(half8*)(xh + o) = h;
    }
    {   // job 2: transpose; block = one (b, d) row of xhT
        const int bd = blockIdx.x;
        const int b = bd >> 9, d = bd & 511;
        const int t0 = threadIdx.x * 8;
        const float* p = x + (size_t)b * (S_ * D_) + (size_t)t0 * D_ + d;
        half8 h;
#pragma unroll
        for (int i = 0; i < 8; i++) h[i] = (_Float16)p[(size_t)i * D_];
        *(half8*)(xhT + (size_t)b * (S_ * D_) + (size_t)d * S_ + t0) = h;
    }
}

// ---------------- GEMM: qw_h = fp16( (x @ W) * inv_scale ) ----------------
__global__ __launch_bounds__(256) void xw_gemm_h(const float* __restrict__ A,
                                                 const float* __restrict__ W,
                                                 _Float16* __restrict__ C) {
    __shared__ float As[16][65];
    __shared__ float Bs[16][64];
    const int tid  = threadIdx.x;
    const int row0 = blockIdx.y * 64;
    const int col0 = blockIdx.x * 64;
    const int ty = tid / 16, tx = tid % 16;

    float acc[4][4] = {};
    const int ar = tid / 4;
    const int ak = (tid % 4) * 4;
    const int bk = tid / 16;
    const int bn = (tid % 16) * 4;

    for (int k0 = 0; k0 < 512; k0 += 16) {
        float4 a4 = *(const float4*)(A + (size_t)(row0 + ar) * 512 + k0 + ak);
        float4 b4 = *(const float4*)(W + (size_t)(k0 + bk) * 512 + col0 + bn);
        __syncthreads();
        As[ak + 0][ar] = a4.x; As[ak + 1][ar] = a4.y;
        As[ak + 2][ar] = a4.z; As[ak + 3][ar] = a4.w;
        *(float4*)&Bs[bk][bn] = b4;
        __syncthreads();
#pragma unroll
        for (int kk = 0; kk < 16; kk++) {
            float a[4], b[4];
#pragma unroll
            for (int i = 0; i < 4; i++) a[i] = As[kk][ty * 4 + i];
#pragma unroll
            for (int j = 0; j < 4; j++) b[j] = Bs[kk][tx * 4 + j];
#pragma unroll
            for (int i = 0; i < 4; i++)
#pragma unroll
                for (int j = 0; j < 4; j++)
                    acc[i][j] += a[i] * b[j];
        }
    }
#pragma unroll
    for (int i = 0; i < 4; i++) {
        half4h h = { (_Float16)(acc[i][0] * INV_SCALE), (_Float16)(acc[i][1] * INV_SCALE),
                     (_Float16)(acc[i][2] * INV_SCALE), (_Float16)(acc[i][3] * INV_SCALE) };
        *(half4h*)(C + (size_t)(row0 + ty * 4 + i) * 512 + col0 + tx * 4) = h;
    }
}

// ---------------- MFMA flash attention (fp16 inputs, fp32 accum) ----------------
// TQ=32 queries/block, TK=64 keys/tile, 4 waves.
// QK^T: compute S^T[t][q] = K·Q^T — wave w owns t-rows [w*16, w*16+16), both q-subtiles.
//   A-frag = x_h[t][d] streamed from global; B-frag = Q from LDS.
// PV: wave w owns d-cols [w*128, w*128+128); A = P from LDS, B = x_hT[d][t] from global.
#define QROW 520   // 512 + 8 pad halves -> row stride 260 dwords ≡ 4 (mod 32): 2-way (free)
#define PROW 72    // 64 + 8 pad halves  -> 36 dwords ≡ 4 (mod 32)

__global__ __launch_bounds__(256, 2) void flash_fp16(const _Float16* __restrict__ xh,
                                                     const _Float16* __restrict__ xhT,
                                                     const _Float16* __restrict__ qwh,
                                                     float* __restrict__ out) {
    __shared__ _Float16 Qs[32 * QROW];
    __shared__ _Float16 Ps[32 * PROW];
    __shared__ float smM[32 * 4];
    __shared__ float smR[32 * 4];

    const int tid = threadIdx.x;
    const int w = tid >> 6, lane = tid & 63, quad = lane >> 4, l16 = lane & 15;
    const int bx = blockIdx.x;
    const int b = bx & 7;            // XCD swizzle: batch -> XCD for L2 locality
    const int q0 = (bx >> 3) * 32;
    const size_t xb = (size_t)b * (S_ * D_);

    // stage Q (32 rows x 512 halves) into LDS
#pragma unroll
    for (int it = 0; it < 8; it++) {
        int c = tid + it * 256;
        int row = c >> 6, c8 = c & 63;
        *(uint4*)&Qs[row * QROW + c8 * 8] =
            *(const uint4*)(qwh + xb + (size_t)(q0 + row) * 512 + c8 * 8);
    }
    __syncthreads();

    f32x4 O[2][8];
#pragma unroll
    for (int qs = 0; qs < 2; qs++)
#pragma unroll
        for (int s = 0; s < 8; s++) O[qs][s] = (f32x4){0.f, 0.f, 0.f, 0.f};
    float m0 = -1e30f, m1 = -1e30f, l0 = 0.f, l1 = 0.f;

    for (int t0 = 0; t0 < S_; t0 += 64) {
        // ---- QK^T: S^T subtiles, accumulate over d ----
        f32x4 s0 = {0.f, 0.f, 0.f, 0.f}, s1 = {0.f, 0.f, 0.f, 0.f};
        const _Float16* ka = xh + xb + (size_t)(t0 + w * 16 + l16) * 512 + quad * 8;
        const _Float16* qb0 = &Qs[l16 * QROW + quad * 8];
        const _Float16* qb1 = &Qs[(16 + l16) * QROW + quad * 8];
#pragma unroll
        for (int ks = 0; ks < 16; ks++) {
            half8 Af = *(const half8*)(ka + ks * 32);
            half8 B0 = *(const half8*)(qb0 + ks * 32);
            half8 B1 = *(const half8*)(qb1 + ks * 32);
            s0 = __builtin_amdgcn_mfma_f32_16x16x32_f16(Af, B0, s0, 0, 0, 0);
            s1 = __builtin_amdgcn_mfma_f32_16x16x32_f16(Af, B1, s1, 0, 0, 0);
        }
        // ---- local row-max over this wave's 16 t's ----
        float M0 = fmaxf(fmaxf(s0[0], s0[1]), fmaxf(s0[2], s0[3]));
        float M1 = fmaxf(fmaxf(s1[0], s1[1]), fmaxf(s1[2], s1[3]));
        M0 = fmaxf(M0, __shfl_xor(M0, 16)); M0 = fmaxf(M0, __shfl_xor(M0, 32));
        M1 = fmaxf(M1, __shfl_xor(M1, 16)); M1 = fmaxf(M1, __shfl_xor(M1, 32));
        if (quad == 0) {
            smM[l16 * 4 + w] = M0;
            smM[(16 + l16) * 4 + w] = M1;
        }
        __syncthreads();
        // ---- combine maxes, compute P = exp(S - m_new), row-sums ----
        float4 Ma = *(float4*)&smM[l16 * 4];
        float4 Mb = *(float4*)&smM[(16 + l16) * 4];
        float mn0 = fmaxf(m0, fmaxf(fmaxf(Ma.x, Ma.y), fmaxf(Ma.z, Ma.w)));
        float mn1 = fmaxf(m1, fmaxf(fmaxf(Mb.x, Mb.y), fmaxf(Mb.z, Mb.w)));
        float a0 = __expf(m0 - mn0), a1 = __expf(m1 - mn1);
        m0 = mn0; m1 = mn1;
        float p0[4], p1[4];
#pragma unroll
        for (int r = 0; r < 4; r++) { p0[r] = __expf(s0[r] - mn0); p1[r] = __expf(s1[r] - mn1); }
        float R0 = p0[0] + p0[1] + p0[2] + p0[3];
        float R1 = p1[0] + p1[1] + p1[2] + p1[3];
        R0 += __shfl_xor(R0, 16); R0 += __shfl_xor(R0, 32);
        R1 += __shfl_xor(R1, 16); R1 += __shfl_xor(R1, 32);
        if (quad == 0) {
            smR[l16 * 4 + w] = R0;
            smR[(16 + l16) * 4 + w] = R1;
        }
        half4h h0 = { (_Float16)p0[0], (_Float16)p0[1], (_Float16)p0[2], (_Float16)p0[3] };
        half4h h1 = { (_Float16)p1[0], (_Float16)p1[1], (_Float16)p1[2], (_Float16)p1[3] };
        *(half4h*)&Ps[l16 * PROW + w * 16 + quad * 4] = h0;
        *(half4h*)&Ps[(16 + l16) * PROW + w * 16 + quad * 4] = h1;
        __syncthreads();
        float4 Ra = *(float4*)&smR[l16 * 4];
        float4 Rb = *(float4*)&smR[(16 + l16) * 4];
        l0 = a0 * l0 + (Ra.x + Ra.y + Ra.z + Ra.w);
        l1 = a1 * l1 + (Rb.x + Rb.y + Rb.z + Rb.w);
        // ---- rescale O if max moved (wave-uniform branch) ----
        if (__any(a0 < 1.f) || __any(a1 < 1.f)) {
            float aq0[4], aq1[4];
#pragma unroll
            for (int r = 0; r < 4; r++) {
                aq0[r] = __shfl(a0, quad * 4 + r);
                aq1[r] = __shfl(a1, quad * 4 + r);
            }
#pragma unroll
            for (int s = 0; s < 8; s++)
#pragma unroll
                for (int r = 0; r < 4; r++) {
                    O[0][s][r] *= aq0[r];
                    O[1][s][r] *= aq1[r];
                }
        }
        // ---- PV: O[q][d] += P·V, B streamed from x_hT ----
        half8 A00 = *(const half8*)&Ps[l16 * PROW + quad * 8];
        half8 A01 = *(const half8*)&Ps[l16 * PROW + 32 + quad * 8];
        half8 A10 = *(const half8*)&Ps[(16 + l16) * PROW + quad * 8];
        half8 A11 = *(const half8*)&Ps[(16 + l16) * PROW + 32 + quad * 8];
        const _Float16* vb = xhT + xb + (size_t)(w * 128 + l16) * S_ + t0 + quad * 8;
#pragma unroll
        for (int s = 0; s < 8; s++) {
            half8 B0 = *(const half8*)(vb + (size_t)(s * 16) * S_);
            half8 B1 = *(const half8*)(vb + (size_t)(s * 16) * S_ + 32);
            O[0][s] = __builtin_amdgcn_mfma_f32_16x16x32_f16(A00, B0, O[0][s], 0, 0, 0);
            O[0][s] = __builtin_amdgcn_mfma_f32_16x16x32_f16(A01, B1, O[0][s], 0, 0, 0);
            O[1][s] = __builtin_amdgcn_mfma_f32_16x16x32_f16(A10, B0, O[1][s], 0, 0, 0);
            O[1][s] = __builtin_amdgcn_mfma_f32_16x16x32_f16(A11, B1, O[1][s], 0, 0, 0);
        }
    }
    // ---- epilogue: out = O / l ----
    float inv0[4], inv1[4];
#pragma unroll
    for (int r = 0; r < 4; r++) {
        inv0[r] = 1.0f / __shfl(l0, quad * 4 + r);
        inv1[r] = 1.0f / __shfl(l1, quad * 4 + r);
    }
#pragma unroll
    for (int qs = 0; qs < 2; qs++)
#pragma unroll
        for (int s = 0; s < 8; s++)
#pragma unroll
            for (int r = 0; r < 4; r++) {
                float v = O[qs][s][r] * (qs ? inv1[r] : inv0[r]);
                out[xb + (size_t)(q0 + qs * 16 + quad * 4 + r) * 512 + w * 128 + s * 16 + l16] = v;
            }
}

// ---------------- fallback fp32 path (round 1, used if ws too small) ----------------
__global__ __launch_bounds__(256) void xw_gemm_f32(const float* __restrict__ A,
                                                   const float* __restrict__ W,
                                                   float* __restrict__ C) {
    __shared__ float As[16][65];
    __shared__ float Bs[16][64];
    const int tid  = threadIdx.x;
    const int row0 = blockIdx.y * 64;
    const int col0 = blockIdx.x * 64;
    const int ty = tid / 16, tx = tid % 16;
    float acc[4][4] = {};
    const int ar = tid / 4, ak = (tid % 4) * 4, bk = tid / 16, bn = (tid % 16) * 4;
    for (int k0 = 0; k0 < 512; k0 += 16) {
        float4 a4 = *(const float4*)(A + (size_t)(row0 + ar) * 512 + k0 + ak);
        float4 b4 = *(const float4*)(W + (size_t)(k0 + bk) * 512 + col0 + bn);
        __syncthreads();
        As[ak + 0][ar] = a4.x; As[ak + 1][ar] = a4.y;
        As[ak + 2][ar] = a4.z; As[ak + 3][ar] = a4.w;
        *(float4*)&Bs[bk][bn] = b4;
        __syncthreads();
#pragma unroll
        for (int kk = 0; kk < 16; kk++) {
            float a[4], b[4];
#pragma unroll
            for (int i = 0; i < 4; i++) a[i] = As[kk][ty * 4 + i];
#pragma unroll
            for (int j = 0; j < 4; j++) b[j] = Bs[kk][tx * 4 + j];
#pragma unroll
            for (int i = 0; i < 4; i++)
#pragma unroll
                for (int j = 0; j < 4; j++) acc[i][j] += a[i] * b[j];
        }
    }
#pragma unroll
    for (int i = 0; i < 4; i++) {
        float4 o = make_float4(acc[i][0] * INV_SCALE, acc[i][1] * INV_SCALE,
                               acc[i][2] * INV_SCALE, acc[i][3] * INV_SCALE);
        *(float4*)(C + (size_t)(row0 + ty * 4 + i) * 512 + col0 + tx * 4) = o;
    }
}

__global__ __launch_bounds__(256) void flash_f32(const float* __restrict__ x,
                                                 const float* __restrict__ qw,
                                                 float* __restrict__ out) {
    __shared__ float4 kt[16 * 136];
    const int tid = threadIdx.x;
    const int q = tid >> 3, g = tid & 7;
    const int blk = blockIdx.x;
    const int b = blk >> 6;
    const int qrow = (blk & 63) * 32 + q;
    const size_t xbase = (size_t)b * S_ * D_;
    float qwr[64];
    {
        const float4* p = (const float4*)(qw + xbase + (size_t)qrow * D_ + g * 64);
#pragma unroll
        for (int i4 = 0; i4 < 16; i4++) {
            float4 v = p[i4];
            qwr[4 * i4 + 0] = v.x; qwr[4 * i4 + 1] = v.y;
            qwr[4 * i4 + 2] = v.z; qwr[4 * i4 + 3] = v.w;
        }
    }
    float oa[64];
#pragma unroll
    for (int i = 0; i < 64; i++) oa[i] = 0.f;
    float m = -1e30f, l = 0.f;
    const float4* x4 = (const float4*)(x + xbase);
    for (int t0 = 0; t0 < S_; t0 += 16) {
        __syncthreads();
#pragma unroll
        for (int j = 0; j < 8; j++) {
            int f = tid + j * 256;
            int tt = f >> 7, c = f & 127;
            kt[tt * 136 + (c >> 4) * 17 + (c & 15)] = x4[(size_t)(t0 + tt) * 128 + c];
        }
        __syncthreads();
#pragma unroll 1
        for (int tt = 0; tt < 16; tt++) {
            float4 kv[16];
            const float4* kp = &kt[tt * 136 + g * 17];
#pragma unroll
            for (int i4 = 0; i4 < 16; i4++) kv[i4] = kp[i4];
            float s = 0.f;
#pragma unroll
            for (int i4 = 0; i4 < 16; i4++)
                s += qwr[4 * i4] * kv[i4].x + qwr[4 * i4 + 1] * kv[i4].y
                   + qwr[4 * i4 + 2] * kv[i4].z + qwr[4 * i4 + 3] * kv[i4].w;
            s += __shfl_xor(s, 1, 64); s += __shfl_xor(s, 2, 64); s += __shfl_xor(s, 4, 64);
            if (s > m) {
                float alpha = __expf(m - s);
                l *= alpha;
#pragma unroll
                for (int i = 0; i < 64; i++) oa[i] *= alpha;
                m = s;
            }
            float p = __expf(s - m);
            l += p;
#pragma unroll
            for (int i4 = 0; i4 < 16; i4++) {
                oa[4 * i4 + 0] += p * kv[i4].x; oa[4 * i4 + 1] += p * kv[i4].y;
                oa[4 * i4 + 2] += p * kv[i4].z; oa[4 * i4 + 3] += p * kv[i4].w;
            }
        }
    }
    float inv_l = 1.0f / l;
    float4* op = (float4*)(out + xbase + (size_t)qrow * D_ + g * 64);
#pragma unroll
    for (int i4 = 0; i4 < 16; i4++)
        op[i4] = make_float4(oa[4 * i4] * inv_l, oa[4 * i4 + 1] * inv_l,
                             oa[4 * i4 + 2] * inv_l, oa[4 * i4 + 3] * inv_l);
}

extern "C" void kernel_launch(void* const* d_in, const int* in_sizes, int n_in,
                              void* d_out, int out_size, void* d_ws, size_t ws_size,
                              hipStream_t stream) {
    const float* x = (const float*)d_in[0];
    const float* W = (const float*)d_in[1];
    float* out = (float*)d_out;

    const size_t halfBytes = (size_t)B_ * S_ * D_ * sizeof(_Float16); // 16.78 MB
    const size_t need = 3 * halfBytes;                                 // 50.33 MB

    if (ws_size >= need) {
        _Float16* qwh = (_Float16*)d_ws;
        _Float16* xh  = (_Float16*)((char*)d_ws + halfBytes);
        _Float16* xhT = (_Float16*)((char*)d_ws + 2 * halfBytes);
        cvt_tr<<<4096, 256, 0, stream>>>(x, xh, xhT);
        dim3 g1(512 / 64, (B_ * S_) / 64);
        xw_gemm_h<<<g1, 256, 0, stream>>>(x, W, qwh);
        flash_fp16<<<B_ * (S_ / 32), 256, 0, stream>>>(xh, xhT, qwh, out);
    } else {
        const size_t needf = (size_t)B_ * S_ * D_ * sizeof(float);
        float* xw = (ws_size >= needf) ? (float*)d_ws : out;
        dim3 g1(512 / 64, (B_ * S_) / 64);
        xw_gemm_f32<<<g1, 256, 0, stream>>>(x, W, xw);
        flash_f32<<<B_ * (S_ / 32), 256, 0, stream>>>(x, xw, out);
    }
}

// Round 4
// 407.589 us; speedup vs baseline: 4.0307x; 1.2802x over previous
//
#include <hip/hip_runtime.h>
#include <math.h>

#define B_ 8
#define S_ 2048
#define D_ 512
#define HSZ (B_ * S_ * D_)   // 8,388,608 elements

typedef _Float16 half8 __attribute__((ext_vector_type(8)));
typedef _Float16 half4h __attribute__((ext_vector_type(4)));
typedef float f32x4 __attribute__((ext_vector_type(4)));

constexpr float INV_SCALE = 0.044194173824159216f; // 1/sqrt(512)

// ================= cvt_all: fp16 convert + tiled transposes =================
// blocks 0..2047: x tiles (64t x 64d): write xh[t][d] fp16 and xhT[d][t] fp16.
// blocks 2048..2111: W tiles: write WhT[e][d] fp16.
__global__ __launch_bounds__(256) void cvt_all(const float* __restrict__ x,
                                               const float* __restrict__ W,
                                               _Float16* __restrict__ xh,
                                               _Float16* __restrict__ xhT,
                                               _Float16* __restrict__ WhT) {
    __shared__ float T[64 * 65];
    const int tid = threadIdx.x;
    const int blk = blockIdx.x;

    const float* src;
    _Float16* dstT;
    _Float16* dstL;
    int t0, d0, dstTld;
    if (blk < 2048) {
        int b = blk >> 8;          // 256 tiles per batch
        int r = blk & 255;
        t0 = (r >> 3) * 64; d0 = (r & 7) * 64;
        src = x + (size_t)b * (S_ * D_);
        dstT = xhT + (size_t)b * (S_ * D_); dstTld = S_;
        dstL = xh + (size_t)b * (S_ * D_);
    } else {
        int r = blk - 2048;        // 8x8 tiles of W
        t0 = (r >> 3) * 64; d0 = (r & 7) * 64;
        src = W; dstT = WhT; dstTld = 512; dstL = nullptr;
    }

    // 64x64 tile = 1024 float4 = 4 iterations of 256 threads. (BUGFIX: was 16.)
#pragma unroll
    for (int it = 0; it < 4; ++it) {
        int flat = it * 256 + tid;            // 0..1023
        int row = flat >> 4, c4 = (flat & 15) * 4;
        float4 v = *(const float4*)(src + (size_t)(t0 + row) * 512 + d0 + c4);
        T[row * 65 + c4 + 0] = v.x; T[row * 65 + c4 + 1] = v.y;
        T[row * 65 + c4 + 2] = v.z; T[row * 65 + c4 + 3] = v.w;
        if (dstL) {
            half4h h = { (_Float16)v.x, (_Float16)v.y, (_Float16)v.z, (_Float16)v.w };
            *(half4h*)(dstL + (size_t)(t0 + row) * 512 + d0 + c4) = h;
        }
    }
    __syncthreads();
#pragma unroll
    for (int it = 0; it < 2; ++it) {
        int flat = it * 256 + tid;            // 0..511
        int d = flat >> 3, c = (flat & 7) * 8;
        half8 hv;
#pragma unroll
        for (int j = 0; j < 8; ++j) hv[j] = (_Float16)T[(c + j) * 65 + d];
        *(half8*)(dstT + (size_t)(d0 + d) * dstTld + t0 + c) = hv;
    }
}

// ================= MFMA GEMM: qwh = fp16( (xh @ W) * inv_scale ) =============
// C[16384,512]; 128x128 block tile, 4 waves each 128m x 32n. All-global (L2).
__global__ __launch_bounds__(256) void gemm_h(const _Float16* __restrict__ xh,
                                              const _Float16* __restrict__ WhT,
                                              _Float16* __restrict__ qwh) {
    const int tid = threadIdx.x;
    const int w = tid >> 6, lane = tid & 63, quad = lane >> 4, l16 = lane & 15;
    const int n0 = (blockIdx.x & 3) * 128 + w * 32;
    const int m0 = (blockIdx.x >> 2) * 128;

    f32x4 acc[8][2];
#pragma unroll
    for (int mt = 0; mt < 8; ++mt)
#pragma unroll
        for (int nt = 0; nt < 2; ++nt) acc[mt][nt] = (f32x4){0.f, 0.f, 0.f, 0.f};

#pragma unroll 2
    for (int kc = 0; kc < 16; ++kc) {
        half8 Bf[2];
#pragma unroll
        for (int nt = 0; nt < 2; ++nt)
            Bf[nt] = *(const half8*)(WhT + (size_t)(n0 + nt * 16 + l16) * 512 + kc * 32 + quad * 8);
#pragma unroll
        for (int mt = 0; mt < 8; ++mt) {
            half8 Af = *(const half8*)(xh + (size_t)(m0 + mt * 16 + l16) * 512 + kc * 32 + quad * 8);
            acc[mt][0] = __builtin_amdgcn_mfma_f32_16x16x32_f16(Af, Bf[0], acc[mt][0], 0, 0, 0);
            acc[mt][1] = __builtin_amdgcn_mfma_f32_16x16x32_f16(Af, Bf[1], acc[mt][1], 0, 0, 0);
        }
    }
#pragma unroll
    for (int mt = 0; mt < 8; ++mt)
#pragma unroll
        for (int nt = 0; nt < 2; ++nt)
#pragma unroll
            for (int r = 0; r < 4; ++r)
                qwh[(size_t)(m0 + mt * 16 + quad * 4 + r) * 512 + n0 + nt * 16 + l16] =
                    (_Float16)(acc[mt][nt][r] * INV_SCALE);
}

// ================= flash2: split-K MFMA flash attention ======================
// TQ=32 q/block, TK=64 keys/tile, 4 waves, ONE barrier per tile.
// Wave-local softmax with deferred cross-wave correction on P A-frags.
#define QROW 520
#define PROW 72

__global__ __launch_bounds__(256, 3)
void flash2(const _Float16* __restrict__ xh, const _Float16* __restrict__ xhT,
            const _Float16* __restrict__ qwh, _Float16* __restrict__ Opart,
            float2* __restrict__ stats, float* __restrict__ out,
            int tlen, int nsplit) {
    __shared__ _Float16 Qs[32 * QROW];
    __shared__ _Float16 Ps[2][32 * PROW];
    __shared__ float smM[2][32 * 4];
    __shared__ float smR[2][32 * 4];

    const int tid = threadIdx.x;
    const int w = tid >> 6, lane = tid & 63, quad = lane >> 4, l16 = lane & 15;
    const int bx = blockIdx.x;
    const int b = bx & 7;                 // XCD swizzle: one batch per XCD
    const int rest = bx >> 3;
    const int h = rest % nsplit;
    const int q0 = (rest / nsplit) * 32;
    const size_t xb = (size_t)b * (S_ * D_);
    const int tbeg = h * tlen;

    // stage Q tile
#pragma unroll
    for (int it = 0; it < 8; ++it) {
        int c = tid + it * 256;
        int row = c >> 6, c8 = c & 63;
        *(uint4*)&Qs[row * QROW + c8 * 8] =
            *(const uint4*)(qwh + xb + (size_t)(q0 + row) * 512 + c8 * 8);
    }
    __syncthreads();

    f32x4 O[2][8];
#pragma unroll
    for (int qs = 0; qs < 2; ++qs)
#pragma unroll
        for (int s = 0; s < 8; ++s) O[qs][s] = (f32x4){0.f, 0.f, 0.f, 0.f};
    float m0 = -1e30f, m1 = -1e30f, l0 = 0.f, l1 = 0.f;

    const int ntiles = tlen >> 6;
    for (int ti = 0; ti < ntiles; ++ti) {
        const int t0 = tbeg + ti * 64;
        const int buf = ti & 1;
        // ---- QK^T (S^T = K·Q^T), wave owns t-rows [w*16, w*16+16) ----
        f32x4 s0 = {0.f, 0.f, 0.f, 0.f}, s1 = {0.f, 0.f, 0.f, 0.f};
        const _Float16* ka = xh + xb + (size_t)(t0 + w * 16 + l16) * 512 + quad * 8;
        const _Float16* qb0 = &Qs[l16 * QROW + quad * 8];
        const _Float16* qb1 = &Qs[(16 + l16) * QROW + quad * 8];
#pragma unroll
        for (int ks = 0; ks < 16; ++ks) {
            half8 Af = *(const half8*)(ka + ks * 32);
            half8 B0 = *(const half8*)(qb0 + ks * 32);
            half8 B1 = *(const half8*)(qb1 + ks * 32);
            s0 = __builtin_amdgcn_mfma_f32_16x16x32_f16(Af, B0, s0, 0, 0, 0);
            s1 = __builtin_amdgcn_mfma_f32_16x16x32_f16(Af, B1, s1, 0, 0, 0);
        }
        // ---- wave-local max over its 16 t's (per q) ----
        float M0 = fmaxf(fmaxf(s0[0], s0[1]), fmaxf(s0[2], s0[3]));
        float M1 = fmaxf(fmaxf(s1[0], s1[1]), fmaxf(s1[2], s1[3]));
        M0 = fmaxf(M0, __shfl_xor(M0, 16)); M0 = fmaxf(M0, __shfl_xor(M0, 32));
        M1 = fmaxf(M1, __shfl_xor(M1, 16)); M1 = fmaxf(M1, __shfl_xor(M1, 32));
        // ---- local p = exp(s - M_local), local row-sums ----
        float p0[4], p1[4];
#pragma unroll
        for (int r = 0; r < 4; ++r) { p0[r] = __expf(s0[r] - M0); p1[r] = __expf(s1[r] - M1); }
        float R0 = p0[0] + p0[1] + p0[2] + p0[3];
        float R1 = p1[0] + p1[1] + p1[2] + p1[3];
        R0 += __shfl_xor(R0, 16); R0 += __shfl_xor(R0, 32);
        R1 += __shfl_xor(R1, 16); R1 += __shfl_xor(R1, 32);
        if (quad == 0) {
            smM[buf][l16 * 4 + w] = M0;        smR[buf][l16 * 4 + w] = R0;
            smM[buf][(16 + l16) * 4 + w] = M1; smR[buf][(16 + l16) * 4 + w] = R1;
        }
        half4h h0 = { (_Float16)p0[0], (_Float16)p0[1], (_Float16)p0[2], (_Float16)p0[3] };
        half4h h1 = { (_Float16)p1[0], (_Float16)p1[1], (_Float16)p1[2], (_Float16)p1[3] };
        _Float16* Pb = Ps[buf];
        *(half4h*)&Pb[l16 * PROW + w * 16 + quad * 4] = h0;
        *(half4h*)&Pb[(16 + l16) * PROW + w * 16 + quad * 4] = h1;
        __syncthreads();   // the ONLY barrier in the tile loop
        // ---- merge stats: m_new, alpha, per-source-wave corrections ----
        float4 Ma = *(float4*)&smM[buf][l16 * 4];
        float4 Mb = *(float4*)&smM[buf][(16 + l16) * 4];
        float mn0 = fmaxf(m0, fmaxf(fmaxf(Ma.x, Ma.y), fmaxf(Ma.z, Ma.w)));
        float mn1 = fmaxf(m1, fmaxf(fmaxf(Mb.x, Mb.y), fmaxf(Mb.z, Mb.w)));
        float a0 = __expf(m0 - mn0), a1 = __expf(m1 - mn1);
        float c00 = __expf(Ma.x - mn0), c01 = __expf(Ma.y - mn0),
              c02 = __expf(Ma.z - mn0), c03 = __expf(Ma.w - mn0);
        float c10 = __expf(Mb.x - mn1), c11 = __expf(Mb.y - mn1),
              c12 = __expf(Mb.z - mn1), c13 = __expf(Mb.w - mn1);
        float4 Ra = *(float4*)&smR[buf][l16 * 4];
        float4 Rb = *(float4*)&smR[buf][(16 + l16) * 4];
        l0 = a0 * l0 + Ra.x * c00 + Ra.y * c01 + Ra.z * c02 + Ra.w * c03;
        l1 = a1 * l1 + Rb.x * c10 + Rb.y * c11 + Rb.z * c12 + Rb.w * c13;
        m0 = mn0; m1 = mn1;
        // ---- rescale O when max moved ----
        if (__any(a0 < 1.f) || __any(a1 < 1.f)) {
            float aq0[4], aq1[4];
#pragma unroll
            for (int r = 0; r < 4; ++r) {
                aq0[r] = __shfl(a0, quad * 4 + r);
                aq1[r] = __shfl(a1, quad * 4 + r);
            }
#pragma unroll
            for (int s = 0; s < 8; ++s)
#pragma unroll
                for (int r = 0; r < 4; ++r) { O[0][s][r] *= aq0[r]; O[1][s][r] *= aq1[r]; }
        }
        // ---- P A-frags with deferred correction, then PV ----
        half8 A00 = *(const half8*)&Pb[l16 * PROW + quad * 8];
        half8 A01 = *(const half8*)&Pb[l16 * PROW + 32 + quad * 8];
        half8 A10 = *(const half8*)&Pb[(16 + l16) * PROW + quad * 8];
        half8 A11 = *(const half8*)&Pb[(16 + l16) * PROW + 32 + quad * 8];
        _Float16 s00 = (_Float16)((quad < 2) ? c00 : c01);
        _Float16 s01 = (_Float16)((quad < 2) ? c02 : c03);
        _Float16 s10 = (_Float16)((quad < 2) ? c10 : c11);
        _Float16 s11 = (_Float16)((quad < 2) ? c12 : c13);
#pragma unroll
        for (int j = 0; j < 8; ++j) {
            A00[j] *= s00; A01[j] *= s01; A10[j] *= s10; A11[j] *= s11;
        }
        const _Float16* vb = xhT + xb + (size_t)(w * 128 + l16) * S_ + t0 + quad * 8;
#pragma unroll
        for (int s = 0; s < 8; ++s) {
            half8 B0 = *(const half8*)(vb + (size_t)(s * 16) * S_);
            half8 B1 = *(const half8*)(vb + (size_t)(s * 16) * S_ + 32);
            O[0][s] = __builtin_amdgcn_mfma_f32_16x16x32_f16(A00, B0, O[0][s], 0, 0, 0);
            O[0][s] = __builtin_amdgcn_mfma_f32_16x16x32_f16(A01, B1, O[0][s], 0, 0, 0);
            O[1][s] = __builtin_amdgcn_mfma_f32_16x16x32_f16(A10, B0, O[1][s], 0, 0, 0);
            O[1][s] = __builtin_amdgcn_mfma_f32_16x16x32_f16(A11, B1, O[1][s], 0, 0, 0);
        }
    }
    // ---- epilogue ----
    float inv0[4], inv1[4];
#pragma unroll
    for (int r = 0; r < 4; ++r) {
        inv0[r] = 1.0f / __shfl(l0, quad * 4 + r);
        inv1[r] = 1.0f / __shfl(l1, quad * 4 + r);
    }
    if (nsplit == 1) {
#pragma unroll
        for (int qs = 0; qs < 2; ++qs)
#pragma unroll
            for (int s = 0; s < 8; ++s)
#pragma unroll
                for (int r = 0; r < 4; ++r) {
                    float v = O[qs][s][r] * (qs ? inv1[r] : inv0[r]);
                    out[xb + (size_t)(q0 + qs * 16 + quad * 4 + r) * 512 + w * 128 + s * 16 + l16] = v;
                }
    } else {
        _Float16* Od = Opart + (size_t)h * HSZ + xb;
#pragma unroll
        for (int qs = 0; qs < 2; ++qs)
#pragma unroll
            for (int s = 0; s < 8; ++s)
#pragma unroll
                for (int r = 0; r < 4; ++r) {
                    float v = O[qs][s][r] * (qs ? inv1[r] : inv0[r]);
                    Od[(size_t)(q0 + qs * 16 + quad * 4 + r) * 512 + w * 128 + s * 16 + l16] = (_Float16)v;
                }
        if (w == 0 && quad == 0) {
            stats[(size_t)(h * B_ + b) * S_ + q0 + l16]      = make_float2(m0, l0);
            stats[(size_t)(h * B_ + b) * S_ + q0 + 16 + l16] = make_float2(m1, l1);
        }
    }
}

// ================= combine: merge split-K partials ===========================
__global__ __launch_bounds__(256) void combine(const _Float16* __restrict__ Op,
                                               const float2* __restrict__ st,
                                               float* __restrict__ out, int nsplit) {
    const int idx = blockIdx.x * 256 + threadIdx.x;   // 1,048,576 chunks of 8
    const int row = idx >> 6;
    const int c = (idx & 63) * 8;
    float m = -3.0e38f;
    float2 sv[4];
#pragma unroll
    for (int hh = 0; hh < 4; ++hh) {
        if (hh < nsplit) { sv[hh] = st[(size_t)hh * (B_ * S_) + row]; m = fmaxf(m, sv[hh].x); }
    }
    float Wt = 0.f, wgt[4];
#pragma unroll
    for (int hh = 0; hh < 4; ++hh) {
        if (hh < nsplit) { wgt[hh] = sv[hh].y * __expf(sv[hh].x - m); Wt += wgt[hh]; }
    }
    float rW = 1.f / Wt;
    float a[8] = {0.f, 0.f, 0.f, 0.f, 0.f, 0.f, 0.f, 0.f};
#pragma unroll
    for (int hh = 0; hh < 4; ++hh) {
        if (hh < nsplit) {
            half8 o = *(const half8*)(Op + (size_t)hh * HSZ + (size_t)row * 512 + c);
            float f = wgt[hh] * rW;
#pragma unroll
            for (int j = 0; j < 8; ++j) a[j] += f * (float)o[j];
        }
    }
    float4 o0 = make_float4(a[0], a[1], a[2], a[3]);
    float4 o1 = make_float4(a[4], a[5], a[6], a[7]);
    *(float4*)(out + (size_t)row * 512 + c) = o0;
    *(float4*)(out + (size_t)row * 512 + c + 4) = o1;
}

// ================= fp32 fallback (round 1) ==================================
__global__ __launch_bounds__(256) void xw_gemm_f32(const float* __restrict__ A,
                                                   const float* __restrict__ W,
                                                   float* __restrict__ C) {
    __shared__ float As[16][65];
    __shared__ float Bs[16][64];
    const int tid = threadIdx.x;
    const int row0 = blockIdx.y * 64, col0 = blockIdx.x * 64;
    const int ty = tid / 16, tx = tid % 16;
    float acc[4][4] = {};
    const int ar = tid / 4, ak = (tid % 4) * 4, bk = tid / 16, bn = (tid % 16) * 4;
    for (int k0 = 0; k0 < 512; k0 += 16) {
        float4 a4 = *(const float4*)(A + (size_t)(row0 + ar) * 512 + k0 + ak);
        float4 b4 = *(const float4*)(W + (size_t)(k0 + bk) * 512 + col0 + bn);
        __syncthreads();
        As[ak + 0][ar] = a4.x; As[ak + 1][ar] = a4.y;
        As[ak + 2][ar] = a4.z; As[ak + 3][ar] = a4.w;
        *(float4*)&Bs[bk][bn] = b4;
        __syncthreads();
#pragma unroll
        for (int kk = 0; kk < 16; kk++) {
            float a[4], b[4];
#pragma unroll
            for (int i = 0; i < 4; i++) a[i] = As[kk][ty * 4 + i];
#pragma unroll
            for (int j = 0; j < 4; j++) b[j] = Bs[kk][tx * 4 + j];
#pragma unroll
            for (int i = 0; i < 4; i++)
#pragma unroll
                for (int j = 0; j < 4; j++) acc[i][j] += a[i] * b[j];
        }
    }
#pragma unroll
    for (int i = 0; i < 4; i++) {
        float4 o = make_float4(acc[i][0] * INV_SCALE, acc[i][1] * INV_SCALE,
                               acc[i][2] * INV_SCALE, acc[i][3] * INV_SCALE);
        *(float4*)(C + (size_t)(row0 + ty * 4 + i) * 512 + col0 + tx * 4) = o;
    }
}

__global__ __launch_bounds__(256) void flash_f32(const float* __restrict__ x,
                                                 const float* __restrict__ qw,
                                                 float* __restrict__ out) {
    __shared__ float4 kt[16 * 136];
    const int tid = threadIdx.x;
    const int q = tid >> 3, g = tid & 7;
    const int blk = blockIdx.x;
    const int b = blk >> 6;
    const int qrow = (blk & 63) * 32 + q;
    const size_t xbase = (size_t)b * S_ * D_;
    float qwr[64];
    {
        const float4* p = (const float4*)(qw + xbase + (size_t)qrow * D_ + g * 64);
#pragma unroll
        for (int i4 = 0; i4 < 16; i4++) {
            float4 v = p[i4];
            qwr[4 * i4 + 0] = v.x; qwr[4 * i4 + 1] = v.y;
            qwr[4 * i4 + 2] = v.z; qwr[4 * i4 + 3] = v.w;
        }
    }
    float oa[64];
#pragma unroll
    for (int i = 0; i < 64; i++) oa[i] = 0.f;
    float m = -1e30f, l = 0.f;
    const float4* x4 = (const float4*)(x + xbase);
    for (int t0 = 0; t0 < S_; t0 += 16) {
        __syncthreads();
#pragma unroll
        for (int j = 0; j < 8; j++) {
            int f = tid + j * 256;
            int tt = f >> 7, c = f & 127;
            kt[tt * 136 + (c >> 4) * 17 + (c & 15)] = x4[(size_t)(t0 + tt) * 128 + c];
        }
        __syncthreads();
#pragma unroll 1
        for (int tt = 0; tt < 16; tt++) {
            float4 kv[16];
            const float4* kp = &kt[tt * 136 + g * 17];
#pragma unroll
            for (int i4 = 0; i4 < 16; i4++) kv[i4] = kp[i4];
            float s = 0.f;
#pragma unroll
            for (int i4 = 0; i4 < 16; i4++)
                s += qwr[4 * i4] * kv[i4].x + qwr[4 * i4 + 1] * kv[i4].y
                   + qwr[4 * i4 + 2] * kv[i4].z + qwr[4 * i4 + 3] * kv[i4].w;
            s += __shfl_xor(s, 1, 64); s += __shfl_xor(s, 2, 64); s += __shfl_xor(s, 4, 64);
            if (s > m) {
                float alpha = __expf(m - s);
                l *= alpha;
#pragma unroll
                for (int i = 0; i < 64; i++) oa[i] *= alpha;
                m = s;
            }
            float p = __expf(s - m);
            l += p;
#pragma unroll
            for (int i4 = 0; i4 < 16; i4++) {
                oa[4 * i4 + 0] += p * kv[i4].x; oa[4 * i4 + 1] += p * kv[i4].y;
                oa[4 * i4 + 2] += p * kv[i4].z; oa[4 * i4 + 3] += p * kv[i4].w;
            }
        }
    }
    float inv_l = 1.0f / l;
    float4* op = (float4*)(out + xbase + (size_t)qrow * D_ + g * 64);
#pragma unroll
    for (int i4 = 0; i4 < 16; i4++)
        op[i4] = make_float4(oa[4 * i4] * inv_l, oa[4 * i4 + 1] * inv_l,
                             oa[4 * i4 + 2] * inv_l, oa[4 * i4 + 3] * inv_l);
}

// ================= launch ====================================================
extern "C" void kernel_launch(void* const* d_in, const int* in_sizes, int n_in,
                              void* d_out, int out_size, void* d_ws, size_t ws_size,
                              hipStream_t stream) {
    const float* x = (const float*)d_in[0];
    const float* W = (const float*)d_in[1];
    float* out = (float*)d_out;

    const size_t F16 = (size_t)HSZ * sizeof(_Float16);     // 16,777,216
    const size_t off_qwh = 0;
    const size_t off_xh  = F16;
    const size_t off_xhT = 2 * F16;
    const size_t off_WhT = 3 * F16;
    const size_t base    = 3 * F16 + 512 * 512 * sizeof(_Float16);   // 50,855,936
    const size_t off_Op  = base;

    int nsplit = 0;
    if (ws_size >= base + 4 * F16 + 4 * (size_t)(B_ * S_) * sizeof(float2)) nsplit = 4;
    else if (ws_size >= base + 2 * F16 + 2 * (size_t)(B_ * S_) * sizeof(float2)) nsplit = 2;
    else if (ws_size >= base) nsplit = 1;

    if (nsplit > 0) {
        _Float16* qwh = (_Float16*)((char*)d_ws + off_qwh);
        _Float16* xh  = (_Float16*)((char*)d_ws + off_xh);
        _Float16* xhT = (_Float16*)((char*)d_ws + off_xhT);
        _Float16* WhT = (_Float16*)((char*)d_ws + off_WhT);
        _Float16* Op  = (nsplit > 1) ? (_Float16*)((char*)d_ws + off_Op) : nullptr;
        float2*   st  = (nsplit > 1) ? (float2*)((char*)d_ws + off_Op + (size_t)nsplit * F16) : nullptr;

        cvt_all<<<2112, 256, 0, stream>>>(x, W, xh, xhT, WhT);
        gemm_h<<<512, 256, 0, stream>>>(xh, WhT, qwh);
        flash2<<<B_ * (S_ / 32) * nsplit, 256, 0, stream>>>(xh, xhT, qwh, Op, st, out,
                                                            S_ / nsplit, nsplit);
        if (nsplit > 1) combine<<<(B_ * S_ * D_ / 8) / 256, 256, 0, stream>>>(Op, st, out, nsplit);
    } else {
        const size_t needf = (size_t)HSZ * sizeof(float);
        float* xw = (ws_size >= needf) ? (float*)d_ws : out;
        dim3 g1(512 / 64, (B_ * S_) / 64);
        xw_gemm_f32<<<g1, 256, 0, stream>>>(x, W, xw);
        flash_f32<<<B_ * (S_ / 32), 256, 0, stream>>>(x, xw, out);
    }
}

// Round 5
// 372.124 us; speedup vs baseline: 4.4148x; 1.0953x over previous
//
#include <hip/hip_runtime.h>
#include <math.h>

#define B_ 8
#define S_ 2048
#define D_ 512
#define HSZ (B_ * S_ * D_)   // 8,388,608 elements

typedef _Float16 half8 __attribute__((ext_vector_type(8)));
typedef _Float16 half4h __attribute__((ext_vector_type(4)));
typedef float f32x4 __attribute__((ext_vector_type(4)));

constexpr float INV_SCALE = 0.044194173824159216f; // 1/sqrt(512)

// ================= cvt_all: fp16 convert + tiled transposes =================
// blocks 0..2047: x tiles (64t x 64d): write xh[t][d] fp16 and xhT[d][t] fp16.
// blocks 2048..2111: W tiles: write WhT[e][d] fp16.
__global__ __launch_bounds__(256) void cvt_all(const float* __restrict__ x,
                                               const float* __restrict__ W,
                                               _Float16* __restrict__ xh,
                                               _Float16* __restrict__ xhT,
                                               _Float16* __restrict__ WhT) {
    __shared__ float T[64 * 65];
    const int tid = threadIdx.x;
    const int blk = blockIdx.x;

    const float* src;
    _Float16* dstT;
    _Float16* dstL;
    int t0, d0, dstTld;
    if (blk < 2048) {
        int b = blk >> 8;          // 256 tiles per batch
        int r = blk & 255;
        t0 = (r >> 3) * 64; d0 = (r & 7) * 64;
        src = x + (size_t)b * (S_ * D_);
        dstT = xhT + (size_t)b * (S_ * D_); dstTld = S_;
        dstL = xh + (size_t)b * (S_ * D_);
    } else {
        int r = blk - 2048;        // 8x8 tiles of W
        t0 = (r >> 3) * 64; d0 = (r & 7) * 64;
        src = W; dstT = WhT; dstTld = 512; dstL = nullptr;
    }

    // 64x64 tile = 1024 float4 = 4 iterations of 256 threads.
#pragma unroll
    for (int it = 0; it < 4; ++it) {
        int flat = it * 256 + tid;            // 0..1023
        int row = flat >> 4, c4 = (flat & 15) * 4;
        float4 v = *(const float4*)(src + (size_t)(t0 + row) * 512 + d0 + c4);
        T[row * 65 + c4 + 0] = v.x; T[row * 65 + c4 + 1] = v.y;
        T[row * 65 + c4 + 2] = v.z; T[row * 65 + c4 + 3] = v.w;
        if (dstL) {
            half4h h = { (_Float16)v.x, (_Float16)v.y, (_Float16)v.z, (_Float16)v.w };
            *(half4h*)(dstL + (size_t)(t0 + row) * 512 + d0 + c4) = h;
        }
    }
    __syncthreads();
#pragma unroll
    for (int it = 0; it < 2; ++it) {
        int flat = it * 256 + tid;            // 0..511
        int d = flat >> 3, c = (flat & 7) * 8;
        half8 hv;
#pragma unroll
        for (int j = 0; j < 8; ++j) hv[j] = (_Float16)T[(c + j) * 65 + d];
        *(half8*)(dstT + (size_t)(d0 + d) * dstTld + t0 + c) = hv;
    }
}

// ================= MFMA GEMM: qwh = fp16( (xh @ W) * inv_scale ) =============
__global__ __launch_bounds__(256) void gemm_h(const _Float16* __restrict__ xh,
                                              const _Float16* __restrict__ WhT,
                                              _Float16* __restrict__ qwh) {
    const int tid = threadIdx.x;
    const int w = tid >> 6, lane = tid & 63, quad = lane >> 4, l16 = lane & 15;
    const int n0 = (blockIdx.x & 3) * 128 + w * 32;
    const int m0 = (blockIdx.x >> 2) * 128;

    f32x4 acc[8][2];
#pragma unroll
    for (int mt = 0; mt < 8; ++mt)
#pragma unroll
        for (int nt = 0; nt < 2; ++nt) acc[mt][nt] = (f32x4){0.f, 0.f, 0.f, 0.f};

#pragma unroll 2
    for (int kc = 0; kc < 16; ++kc) {
        half8 Bf[2];
#pragma unroll
        for (int nt = 0; nt < 2; ++nt)
            Bf[nt] = *(const half8*)(WhT + (size_t)(n0 + nt * 16 + l16) * 512 + kc * 32 + quad * 8);
#pragma unroll
        for (int mt = 0; mt < 8; ++mt) {
            half8 Af = *(const half8*)(xh + (size_t)(m0 + mt * 16 + l16) * 512 + kc * 32 + quad * 8);
            acc[mt][0] = __builtin_amdgcn_mfma_f32_16x16x32_f16(Af, Bf[0], acc[mt][0], 0, 0, 0);
            acc[mt][1] = __builtin_amdgcn_mfma_f32_16x16x32_f16(Af, Bf[1], acc[mt][1], 0, 0, 0);
        }
    }
#pragma unroll
    for (int mt = 0; mt < 8; ++mt)
#pragma unroll
        for (int nt = 0; nt < 2; ++nt)
#pragma unroll
            for (int r = 0; r < 4; ++r)
                qwh[(size_t)(m0 + mt * 16 + quad * 4 + r) * 512 + n0 + nt * 16 + l16] =
                    (_Float16)(acc[mt][nt][r] * INV_SCALE);
}

// ================= flash3: register-pipelined MFMA flash attention ==========
// TQ=32 q/block, TK=64 keys/tile, 4 waves, ONE barrier per tile, no split-K.
// K/V fragments preloaded into register ARRAYS (batch-issued global loads);
// next-tile K and current-tile V are issued BEFORE the barrier so its vmcnt
// drain completes them behind the softmax VALU work.
#define QROW 520
#define PROW 72

__global__ __launch_bounds__(256, 2)
void flash3(const _Float16* __restrict__ xh, const _Float16* __restrict__ xhT,
            const _Float16* __restrict__ qwh, float* __restrict__ out) {
    __shared__ _Float16 Qs[32 * QROW];
    __shared__ _Float16 Ps[2][32 * PROW];
    __shared__ float smM[2][128];
    __shared__ float smR[2][128];

    const int tid = threadIdx.x;
    const int w = tid >> 6, lane = tid & 63, quad = lane >> 4, l16 = lane & 15;
    const int bx = blockIdx.x;
    const int b = bx & 7;                 // XCD swizzle: one batch per XCD
    const int q0 = (bx >> 3) * 32;
    const size_t xb = (size_t)b * (S_ * D_);

    // stage Q tile (32 rows x 512 halves)
#pragma unroll
    for (int it = 0; it < 8; ++it) {
        int c = tid + it * 256;
        int row = c >> 6, c8 = c & 63;
        *(uint4*)&Qs[row * QROW + c8 * 8] =
            *(const uint4*)(qwh + xb + (size_t)(q0 + row) * 512 + c8 * 8);
    }
    __syncthreads();

    f32x4 O[2][8];
#pragma unroll
    for (int qs = 0; qs < 2; ++qs)
#pragma unroll
        for (int s = 0; s < 8; ++s) O[qs][s] = (f32x4){0.f, 0.f, 0.f, 0.f};
    float m0 = -1e30f, m1 = -1e30f, l0 = 0.f, l1 = 0.f;

    // K fragment base for this wave: row (t0 + w*16 + l16), d-offset quad*8
    const _Float16* kROW = xh + xb + (size_t)(w * 16 + l16) * 512 + quad * 8;
    const _Float16* vROW = xhT + xb + (size_t)(w * 128 + l16) * S_ + quad * 8;

    half8 Kf[16];
#pragma unroll
    for (int ks = 0; ks < 16; ++ks) Kf[ks] = *(const half8*)(kROW + ks * 32);
    half8 Vf[16];

    const int ntiles = S_ / 64;  // 32
    for (int ti = 0; ti < ntiles; ++ti) {
        const int t0 = ti * 64;
        const int buf = ti & 1;
        // ---- QK^T (S^T = K·Q^T): K from regs, Q from LDS ----
        f32x4 s0 = {0.f, 0.f, 0.f, 0.f}, s1 = {0.f, 0.f, 0.f, 0.f};
        const _Float16* qb0 = &Qs[l16 * QROW + quad * 8];
        const _Float16* qb1 = &Qs[(16 + l16) * QROW + quad * 8];
#pragma unroll
        for (int ks = 0; ks < 16; ++ks) {
            half8 B0 = *(const half8*)(qb0 + ks * 32);
            half8 B1 = *(const half8*)(qb1 + ks * 32);
            s0 = __builtin_amdgcn_mfma_f32_16x16x32_f16(Kf[ks], B0, s0, 0, 0, 0);
            s1 = __builtin_amdgcn_mfma_f32_16x16x32_f16(Kf[ks], B1, s1, 0, 0, 0);
        }
        // ---- wave-local max over its 16 t's (per q) ----
        float M0 = fmaxf(fmaxf(s0[0], s0[1]), fmaxf(s0[2], s0[3]));
        float M1 = fmaxf(fmaxf(s1[0], s1[1]), fmaxf(s1[2], s1[3]));
        M0 = fmaxf(M0, __shfl_xor(M0, 16)); M0 = fmaxf(M0, __shfl_xor(M0, 32));
        M1 = fmaxf(M1, __shfl_xor(M1, 16)); M1 = fmaxf(M1, __shfl_xor(M1, 32));
        // ---- local p = exp(s - M_local), local row-sums ----
        float p0[4], p1[4];
#pragma unroll
        for (int r = 0; r < 4; ++r) { p0[r] = __expf(s0[r] - M0); p1[r] = __expf(s1[r] - M1); }
        float R0 = p0[0] + p0[1] + p0[2] + p0[3];
        float R1 = p1[0] + p1[1] + p1[2] + p1[3];
        R0 += __shfl_xor(R0, 16); R0 += __shfl_xor(R0, 32);
        R1 += __shfl_xor(R1, 16); R1 += __shfl_xor(R1, 32);
        if (quad == 0) {
            smM[buf][l16 * 4 + w] = M0;        smR[buf][l16 * 4 + w] = R0;
            smM[buf][(16 + l16) * 4 + w] = M1; smR[buf][(16 + l16) * 4 + w] = R1;
        }
        half4h h0 = { (_Float16)p0[0], (_Float16)p0[1], (_Float16)p0[2], (_Float16)p0[3] };
        half4h h1 = { (_Float16)p1[0], (_Float16)p1[1], (_Float16)p1[2], (_Float16)p1[3] };
        _Float16* Pb = Ps[buf];
        *(half4h*)&Pb[l16 * PROW + w * 16 + quad * 4] = h0;
        *(half4h*)&Pb[(16 + l16) * PROW + w * 16 + quad * 4] = h1;

        // ---- issue next-tile K loads + this-tile V loads BEFORE the barrier:
        //      the barrier's vmcnt drain completes them behind the VALU work.
        {
            const int t0n = (ti + 1 < ntiles) ? t0 + 64 : 0;   // wrap: harmless re-read
            const _Float16* kan = kROW + (size_t)t0n * 512;
#pragma unroll
            for (int ks = 0; ks < 16; ++ks) Kf[ks] = *(const half8*)(kan + ks * 32);
            const _Float16* vb = vROW + t0;
#pragma unroll
            for (int s = 0; s < 8; ++s) {
                Vf[2 * s]     = *(const half8*)(vb + (size_t)(s * 16) * S_);
                Vf[2 * s + 1] = *(const half8*)(vb + (size_t)(s * 16) * S_ + 32);
            }
        }
        __syncthreads();   // the ONLY barrier in the tile loop
        // ---- merge stats: m_new, alpha, per-source-wave corrections ----
        float4 Ma = *(float4*)&smM[buf][l16 * 4];
        float4 Mb = *(float4*)&smM[buf][(16 + l16) * 4];
        float mn0 = fmaxf(m0, fmaxf(fmaxf(Ma.x, Ma.y), fmaxf(Ma.z, Ma.w)));
        float mn1 = fmaxf(m1, fmaxf(fmaxf(Mb.x, Mb.y), fmaxf(Mb.z, Mb.w)));
        float a0 = __expf(m0 - mn0), a1 = __expf(m1 - mn1);
        float c00 = __expf(Ma.x - mn0), c01 = __expf(Ma.y - mn0),
              c02 = __expf(Ma.z - mn0), c03 = __expf(Ma.w - mn0);
        float c10 = __expf(Mb.x - mn1), c11 = __expf(Mb.y - mn1),
              c12 = __expf(Mb.z - mn1), c13 = __expf(Mb.w - mn1);
        float4 Ra = *(float4*)&smR[buf][l16 * 4];
        float4 Rb = *(float4*)&smR[buf][(16 + l16) * 4];
        l0 = a0 * l0 + Ra.x * c00 + Ra.y * c01 + Ra.z * c02 + Ra.w * c03;
        l1 = a1 * l1 + Rb.x * c10 + Rb.y * c11 + Rb.z * c12 + Rb.w * c13;
        m0 = mn0; m1 = mn1;
        // ---- rescale O when max moved ----
        if (__any(a0 < 1.f) || __any(a1 < 1.f)) {
            float aq0[4], aq1[4];
#pragma unroll
            for (int r = 0; r < 4; ++r) {
                aq0[r] = __shfl(a0, quad * 4 + r);
                aq1[r] = __shfl(a1, quad * 4 + r);
            }
#pragma unroll
            for (int s = 0; s < 8; ++s)
#pragma unroll
                for (int r = 0; r < 4; ++r) { O[0][s][r] *= aq0[r]; O[1][s][r] *= aq1[r]; }
        }
        // ---- P A-frags with deferred correction, then PV (V from regs) ----
        half8 A00 = *(const half8*)&Pb[l16 * PROW + quad * 8];
        half8 A01 = *(const half8*)&Pb[l16 * PROW + 32 + quad * 8];
        half8 A10 = *(const half8*)&Pb[(16 + l16) * PROW + quad * 8];
        half8 A11 = *(const half8*)&Pb[(16 + l16) * PROW + 32 + quad * 8];
        _Float16 s00 = (_Float16)((quad < 2) ? c00 : c01);
        _Float16 s01 = (_Float16)((quad < 2) ? c02 : c03);
        _Float16 s10 = (_Float16)((quad < 2) ? c10 : c11);
        _Float16 s11 = (_Float16)((quad < 2) ? c12 : c13);
#pragma unroll
        for (int j = 0; j < 8; ++j) {
            A00[j] *= s00; A01[j] *= s01; A10[j] *= s10; A11[j] *= s11;
        }
#pragma unroll
        for (int s = 0; s < 8; ++s) {
            O[0][s] = __builtin_amdgcn_mfma_f32_16x16x32_f16(A00, Vf[2 * s],     O[0][s], 0, 0, 0);
            O[0][s] = __builtin_amdgcn_mfma_f32_16x16x32_f16(A01, Vf[2 * s + 1], O[0][s], 0, 0, 0);
            O[1][s] = __builtin_amdgcn_mfma_f32_16x16x32_f16(A10, Vf[2 * s],     O[1][s], 0, 0, 0);
            O[1][s] = __builtin_amdgcn_mfma_f32_16x16x32_f16(A11, Vf[2 * s + 1], O[1][s], 0, 0, 0);
        }
    }
    // ---- epilogue: out = O / l ----
    float inv0[4], inv1[4];
#pragma unroll
    for (int r = 0; r < 4; ++r) {
        inv0[r] = 1.0f / __shfl(l0, quad * 4 + r);
        inv1[r] = 1.0f / __shfl(l1, quad * 4 + r);
    }
#pragma unroll
    for (int qs = 0; qs < 2; ++qs)
#pragma unroll
        for (int s = 0; s < 8; ++s)
#pragma unroll
            for (int r = 0; r < 4; ++r) {
                float v = O[qs][s][r] * (qs ? inv1[r] : inv0[r]);
                out[xb + (size_t)(q0 + qs * 16 + quad * 4 + r) * 512 + w * 128 + s * 16 + l16] = v;
            }
}

// ================= fp32 fallback (round 1) ==================================
__global__ __launch_bounds__(256) void xw_gemm_f32(const float* __restrict__ A,
                                                   const float* __restrict__ W,
                                                   float* __restrict__ C) {
    __shared__ float As[16][65];
    __shared__ float Bs[16][64];
    const int tid = threadIdx.x;
    const int row0 = blockIdx.y * 64, col0 = blockIdx.x * 64;
    const int ty = tid / 16, tx = tid % 16;
    float acc[4][4] = {};
    const int ar = tid / 4, ak = (tid % 4) * 4, bk = tid / 16, bn = (tid % 16) * 4;
    for (int k0 = 0; k0 < 512; k0 += 16) {
        float4 a4 = *(const float4*)(A + (size_t)(row0 + ar) * 512 + k0 + ak);
        float4 b4 = *(const float4*)(W + (size_t)(k0 + bk) * 512 + col0 + bn);
        __syncthreads();
        As[ak + 0][ar] = a4.x; As[ak + 1][ar] = a4.y;
        As[ak + 2][ar] = a4.z; As[ak + 3][ar] = a4.w;
        *(float4*)&Bs[bk][bn] = b4;
        __syncthreads();
#pragma unroll
        for (int kk = 0; kk < 16; kk++) {
            float a[4], b[4];
#pragma unroll
            for (int i = 0; i < 4; i++) a[i] = As[kk][ty * 4 + i];
#pragma unroll
            for (int j = 0; j < 4; j++) b[j] = Bs[kk][tx * 4 + j];
#pragma unroll
            for (int i = 0; i < 4; i++)
#pragma unroll
                for (int j = 0; j < 4; j++) acc[i][j] += a[i] * b[j];
        }
    }
#pragma unroll
    for (int i = 0; i < 4; i++) {
        float4 o = make_float4(acc[i][0] * INV_SCALE, acc[i][1] * INV_SCALE,
                               acc[i][2] * INV_SCALE, acc[i][3] * INV_SCALE);
        *(float4*)(C + (size_t)(row0 + ty * 4 + i) * 512 + col0 + tx * 4) = o;
    }
}

__global__ __launch_bounds__(256) void flash_f32(const float* __restrict__ x,
                                                 const float* __restrict__ qw,
                                                 float* __restrict__ out) {
    __shared__ float4 kt[16 * 136];
    const int tid = threadIdx.x;
    const int q = tid >> 3, g = tid & 7;
    const int blk = blockIdx.x;
    const int b = blk >> 6;
    const int qrow = (blk & 63) * 32 + q;
    const size_t xbase = (size_t)b * S_ * D_;
    float qwr[64];
    {
        const float4* p = (const float4*)(qw + xbase + (size_t)qrow * D_ + g * 64);
#pragma unroll
        for (int i4 = 0; i4 < 16; i4++) {
            float4 v = p[i4];
            qwr[4 * i4 + 0] = v.x; qwr[4 * i4 + 1] = v.y;
            qwr[4 * i4 + 2] = v.z; qwr[4 * i4 + 3] = v.w;
        }
    }
    float oa[64];
#pragma unroll
    for (int i = 0; i < 64; i++) oa[i] = 0.f;
    float m = -1e30f, l = 0.f;
    const float4* x4 = (const float4*)(x + xbase);
    for (int t0 = 0; t0 < S_; t0 += 16) {
        __syncthreads();
#pragma unroll
        for (int j = 0; j < 8; j++) {
            int f = tid + j * 256;
            int tt = f >> 7, c = f & 127;
            kt[tt * 136 + (c >> 4) * 17 + (c & 15)] = x4[(size_t)(t0 + tt) * 128 + c];
        }
        __syncthreads();
#pragma unroll 1
        for (int tt = 0; tt < 16; tt++) {
            float4 kv[16];
            const float4* kp = &kt[tt * 136 + g * 17];
#pragma unroll
            for (int i4 = 0; i4 < 16; i4++) kv[i4] = kp[i4];
            float s = 0.f;
#pragma unroll
            for (int i4 = 0; i4 < 16; i4++)
                s += qwr[4 * i4] * kv[i4].x + qwr[4 * i4 + 1] * kv[i4].y
                   + qwr[4 * i4 + 2] * kv[i4].z + qwr[4 * i4 + 3] * kv[i4].w;
            s += __shfl_xor(s, 1, 64); s += __shfl_xor(s, 2, 64); s += __shfl_xor(s, 4, 64);
            if (s > m) {
                float alpha = __expf(m - s);
                l *= alpha;
#pragma unroll
                for (int i = 0; i < 64; i++) oa[i] *= alpha;
                m = s;
            }
            float p = __expf(s - m);
            l += p;
#pragma unroll
            for (int i4 = 0; i4 < 16; i4++) {
                oa[4 * i4 + 0] += p * kv[i4].x; oa[4 * i4 + 1] += p * kv[i4].y;
                oa[4 * i4 + 2] += p * kv[i4].z; oa[4 * i4 + 3] += p * kv[i4].w;
            }
        }
    }
    float inv_l = 1.0f / l;
    float4* op = (float4*)(out + xbase + (size_t)qrow * D_ + g * 64);
#pragma unroll
    for (int i4 = 0; i4 < 16; i4++)
        op[i4] = make_float4(oa[4 * i4] * inv_l, oa[4 * i4 + 1] * inv_l,
                             oa[4 * i4 + 2] * inv_l, oa[4 * i4 + 3] * inv_l);
}

// ================= launch ====================================================
extern "C" void kernel_launch(void* const* d_in, const int* in_sizes, int n_in,
                              void* d_out, int out_size, void* d_ws, size_t ws_size,
                              hipStream_t stream) {
    const float* x = (const float*)d_in[0];
    const float* W = (const float*)d_in[1];
    float* out = (float*)d_out;

    const size_t F16 = (size_t)HSZ * sizeof(_Float16);     // 16,777,216
    const size_t off_qwh = 0;
    const size_t off_xh  = F16;
    const size_t off_xhT = 2 * F16;
    const size_t off_WhT = 3 * F16;
    const size_t base    = 3 * F16 + 512 * 512 * sizeof(_Float16);   // 50,855,936

    if (ws_size >= base) {
        _Float16* qwh = (_Float16*)((char*)d_ws + off_qwh);
        _Float16* xh  = (_Float16*)((char*)d_ws + off_xh);
        _Float16* xhT = (_Float16*)((char*)d_ws + off_xhT);
        _Float16* WhT = (_Float16*)((char*)d_ws + off_WhT);

        cvt_all<<<2112, 256, 0, stream>>>(x, W, xh, xhT, WhT);
        gemm_h<<<512, 256, 0, stream>>>(xh, WhT, qwh);
        flash3<<<B_ * (S_ / 32), 256, 0, stream>>>(xh, xhT, qwh, out);
    } else {
        const size_t needf = (size_t)HSZ * sizeof(float);
        float* xw = (ws_size >= needf) ? (float*)d_ws : out;
        dim3 g1(512 / 64, (B_ * S_) / 64);
        xw_gemm_f32<<<g1, 256, 0, stream>>>(x, W, xw);
        flash_f32<<<B_ * (S_ / 32), 256, 0, stream>>>(x, xw, out);
    }
}